// Round 9
// baseline (215.305 us; speedup 1.0000x reference)
//
#include <hip/hip_runtime.h>
#include <math.h>

#define D 128
#define NNODES 10000
#define NEDGES 16384
#define PADR 136   // bf16 row stride for xjb/rootT; 272B rows, 16B-aligned
#define MAXDEG 16

typedef short short8 __attribute__((ext_vector_type(8)));
typedef float floatx4 __attribute__((ext_vector_type(4)));

__device__ __forceinline__ float bf2f(unsigned short u) {
  union { unsigned u; float f; } v; v.u = ((unsigned)u) << 16; return v.f;
}
__device__ __forceinline__ unsigned short f2bf(float f) {
  union { float f; unsigned u; } v; v.f = f;
  return (unsigned short)((v.u + 0x7FFFu + ((v.u >> 16) & 1u)) >> 16);
}
__device__ __forceinline__ float bflo(unsigned u) {
  union { unsigned u; float f; } v; v.u = u << 16; return v.f;
}
__device__ __forceinline__ float bfhi(unsigned u) {
  union { unsigned u; float f; } v; v.u = u & 0xFFFF0000u; return v.f;
}
__device__ __forceinline__ short8 pack8(float4 a, float4 b) {
  short8 r;
  r[0] = (short)f2bf(a.x); r[1] = (short)f2bf(a.y);
  r[2] = (short)f2bf(a.z); r[3] = (short)f2bf(a.w);
  r[4] = (short)f2bf(b.x); r[5] = (short)f2bf(b.y);
  r[6] = (short)f2bf(b.z); r[7] = (short)f2bf(b.w);
  return r;
}

// K12: merged prep + edge kernel. Grid 1032 (byte-identical to round 8):
//   bid <  516 : w2t k-plane transpose -> MFMA-FRAGMENT layout
//                [k][oq][wg][ks][lane][8]; bid<40 zero cnt
//   516..519   : rootT transpose (PADR layout)
//   bid >= 520 : edge work, 512 blocks x 32 edges; per wave: 16 edges x 64 k.
__global__ __launch_bounds__(256) void k12(
    const float* __restrict__ x, const int* __restrict__ eidx,
    const float* __restrict__ ea,
    const float* __restrict__ w1, const float* __restrict__ b1,
    const float* __restrict__ w2, const float* __restrict__ b2,
    const float* __restrict__ root,
    unsigned short* __restrict__ w2t, unsigned short* __restrict__ rootT,
    unsigned short* __restrict__ hT, unsigned short* __restrict__ xjb,
    int* __restrict__ cnt) {
  __shared__ float L[32][129];            // 16,512 B
  __shared__ unsigned short w1tL[128 * PADR];  // 34,816 B (edge path only)
  const int t = threadIdx.x;
  const int bid = blockIdx.x;

  if (bid < 520) {
    // ---------------- prep path ----------------
    if (bid < 40) { const int gid = bid * 256 + t; if (gid < NNODES) cnt[gid] = 0; }
    const float* __restrict__ src;
    int o0;
    if (bid < 516) {
      const int k = bid >> 2;
      o0 = (bid & 3) * 32;
      src = (k < D) ? (w2 + (long)k * (D * D)) : b2;
    } else {
      o0 = (bid - 516) * 32; src = root;
    }
#pragma unroll
    for (int r = 0; r < 16; ++r) {
      int idx = r * 256 + t;
      int i = idx >> 5, oc = idx & 31;
      L[oc][i] = src[i * D + o0 + oc];
    }
    __syncthreads();
#pragma unroll
    for (int r = 0; r < 8; ++r) {
      int p = r * 256 + t;
      int oc = p >> 6, i2 = (p & 63) * 2;
      unsigned v = (unsigned)f2bf(L[oc][i2]) | ((unsigned)f2bf(L[oc][i2 + 1]) << 16);
      if (bid < 516) {
        const long k = bid >> 2, oq = bid & 3;
        const int wg = oc >> 4, lo = oc & 15;
        const int ks = i2 >> 5, hi = (i2 & 31) >> 3, j = i2 & 7;
        const long off = ((((k * 4 + oq) * 2 + wg) * 4 + ks) * 512) +
                         (lo + 16 * hi) * 8 + j;
        *(unsigned*)(w2t + off) = v;
      } else {
        *(unsigned*)(rootT + ((o0 + oc) * PADR + i2)) = v;
      }
    }
    return;
  }

  // ---------------- edge path: 32 edges/block, w1t from LDS ----------------
  const int e0 = (bid - 520) * 32;
#pragma unroll 4
  for (int r = 0; r < 8; ++r) {
    int idx = r * 256 + t, e = idx >> 6, i2 = (idx & 63) * 2;
    const int s = eidx[e0 + e];
    const float2 v = *(const float2*)(x + (long)s * D + i2);
    unsigned p = (unsigned)f2bf(v.x) | ((unsigned)f2bf(v.y) << 16);
    *(unsigned*)(xjb + ((e0 + e) * PADR + i2)) = p;
  }
  for (int c = 0; c < 4; ++c) {
    const int o0c = c * 32;
#pragma unroll
    for (int r = 0; r < 16; ++r) {
      int idx = r * 256 + t;
      int i = idx >> 5, oc = idx & 31;
      L[oc][i] = w1[i * D + o0c + oc];
    }
    __syncthreads();
#pragma unroll
    for (int r = 0; r < 8; ++r) {
      int p = r * 256 + t;
      int oc = p >> 6, i2 = (p & 63) * 2;
      unsigned v = (unsigned)f2bf(L[oc][i2]) | ((unsigned)f2bf(L[oc][i2 + 1]) << 16);
      *(unsigned*)(w1tL + ((o0c + oc) * PADR + i2)) = v;
    }
    __syncthreads();
  }
  const int lane = t & 63, w = t >> 6, lo = lane & 15, hi = lane >> 4;
  const int e16 = (w & 1) * 16;     // wave's 16-edge group
  const int kh = (w >> 1) * 64;     // wave's k-half
  short8 af[4];
#pragma unroll
  for (int ks = 0; ks < 4; ++ks) {
    const float* p0 = ea + (long)(e0 + e16 + lo) * D + ks * 32 + hi * 8;
    af[ks] = pack8(*(const float4*)p0, *(const float4*)(p0 + 4));
  }
  floatx4 acc[4];
#pragma unroll
  for (int nt = 0; nt < 4; ++nt) acc[nt] = (floatx4){0.f, 0.f, 0.f, 0.f};
#pragma unroll
  for (int ks = 0; ks < 4; ++ks) {
    const int ib = ks * 32 + hi * 8;
#pragma unroll
    for (int nt = 0; nt < 4; ++nt) {
      const short8 bf_ = *(const short8*)&w1tL[(kh + nt * 16 + lo) * PADR + ib];
      acc[nt] = __builtin_amdgcn_mfma_f32_16x16x32_bf16(af[ks], bf_, acc[nt], 0, 0, 0);
    }
  }
#pragma unroll
  for (int nt = 0; nt < 4; ++nt) {
    const int ko = kh + nt * 16 + lo;
    const float b1v = b1[ko];
    float v0 = fmaxf(acc[nt][0] + b1v, 0.f);
    float v1 = fmaxf(acc[nt][1] + b1v, 0.f);
    float v2 = fmaxf(acc[nt][2] + b1v, 0.f);
    float v3 = fmaxf(acc[nt][3] + b1v, 0.f);
    uint2 pk;
    pk.x = (unsigned)f2bf(v0) | ((unsigned)f2bf(v1) << 16);
    pk.y = (unsigned)f2bf(v2) | ((unsigned)f2bf(v3) << 16);
    *(uint2*)(hT + (ko * NEDGES + e0 + e16 + hi * 4)) = pk;
  }
  if (t < 32) hT[128 * NEDGES + e0 + t] = 0x3F80;  // bf16(1.0) ones-row (b2)
}

// K3 = round-7 structure with ONE delta: __launch_bounds__(256,4).
// Fragment-packed A cut the live set to ~84 VGPR + ~32 AGPR ~ 116 unified
// <= 128, so a 4th wave/SIMD now fits: grid 1024 = exactly 4 blocks/CU,
// zero occupancy tail (was 3/CU -> 768 resident + 256-block straggler pass).
// LDS 4 x 33,280 = 133KB <= 160KB.
__global__ __launch_bounds__(256, 4) void k3_msg(
    const unsigned short* __restrict__ w2t,
    const unsigned short* __restrict__ xjb,
    const unsigned short* __restrict__ hT,
    const int* __restrict__ eidx, int* __restrict__ cnt,
    int* __restrict__ elist,
    unsigned short* __restrict__ msgout) {
  __shared__ float hLT[65 * 128];   // 33,280 B; idx = kk*128 + (e>>6)*64 + (e&15)*4 + ((e>>4)&3)
  const int t = threadIdx.x;
  const int b = blockIdx.x;
  const int kh = b & 1;
  const int oq = (b >> 1) & 3;      // (oq,kh) fixed per XCD -> w2t slice L2-hot
  const int eg = b >> 3;
  const int e0 = eg * 128;
  const int o0 = oq * 32;
  const int kbase = kh * 64;
  const int kcnt = kh ? 65 : 64;    // kh1 includes k=128 (b2 ones-row)
  const int lane = t & 63, wv = t >> 6;
  const int lo = lane & 15, hi = lane >> 4;
  const int we = (wv >> 1) * 64;
  const int wg = wv & 1;            // o-group (wo = wg*16)
  const int wo = wg * 16;

  // adjacency build (cnt zeroed by k12, prior dispatch)
  if ((b & 7) == 0 && t < 128) {
    const int e = e0 + t;
    const int d = eidx[NEDGES + e];
    const int pos = atomicAdd(&cnt[d], 1);
    if (pos < MAXDEG) elist[d * MAXDEG + pos] = e;
  }

  // stage hLT (permuted) from hT; 2 edges per thread-iter
  for (int idx = t; idx < kcnt * 64; idx += 256) {
    const int kk = idx >> 6, e2 = (idx & 63) * 2;
    const unsigned u = *(const unsigned*)&hT[(long)(kbase + kk) * NEDGES + e0 + e2];
    const int ebase = kk * 128;
#pragma unroll
    for (int q = 0; q < 2; ++q) {
      const int e = e2 + q;
      hLT[ebase + ((e >> 6) << 6) + ((e & 15) << 2) + ((e >> 4) & 3)] =
          q ? bfhi(u) : bflo(u);
    }
  }

  // xf from xjb (k-invariant, b128, no conversion)
  short8 xf[4][4];
#pragma unroll
  for (int ne = 0; ne < 4; ++ne)
#pragma unroll
    for (int ks = 0; ks < 4; ++ks)
      xf[ne][ks] = *(const short8*)&xjb[(long)(e0 + we + ne * 16 + lo) * PADR + ks * 32 + hi * 8];
  __syncthreads();  // the only barrier

  // fragment-packed A: frag(k, ks) at ((((k*4+oq)*2+wg)*4+ks)*512 + lane*8
  const long PLANE = (long)D * D;   // 16384 shorts between consecutive k
  const unsigned short* ap =
      w2t + ((((long)kbase * 4 + oq) * 2 + wg) * 4) * 512 + lane * 8;
  const float* hp = hLT + we + lo * 4;
  short8 a0[4], a1[4];
#pragma unroll
  for (int ks = 0; ks < 4; ++ks) a0[ks] = *(const short8*)(ap + ks * 512);
#pragma unroll
  for (int ks = 0; ks < 4; ++ks) a1[ks] = *(const short8*)(ap + PLANE + ks * 512);
  floatx4 msg[4];
#pragma unroll
  for (int ne = 0; ne < 4; ++ne) msg[ne] = (floatx4){0.f, 0.f, 0.f, 0.f};

  auto body = [&](short8* fr, int k) {
    const floatx4 h4 = *(const floatx4*)(hp + k * 128);
    floatx4 P[4];
#pragma unroll
    for (int ne = 0; ne < 4; ++ne) P[ne] = (floatx4){0.f, 0.f, 0.f, 0.f};
#pragma unroll
    for (int ks = 0; ks < 4; ++ks)
#pragma unroll
      for (int ne = 0; ne < 4; ++ne)
        P[ne] = __builtin_amdgcn_mfma_f32_16x16x32_bf16(fr[ks], xf[ne][ks], P[ne], 0, 0, 0);
#pragma unroll
    for (int ne = 0; ne < 4; ++ne)
#pragma unroll
      for (int r = 0; r < 4; ++r) msg[ne][r] += h4[ne] * P[ne][r];
  };

  const int kpairs = kcnt >> 1;
  for (int j = 0; j < kpairs; ++j) {
    const int k = j * 2;
    body(a0, k);
    {
      const int kp = (k + 2 < kcnt) ? k + 2 : 0;
#pragma unroll
      for (int ks = 0; ks < 4; ++ks)
        a0[ks] = *(const short8*)(ap + (long)kp * PLANE + ks * 512);
    }
    body(a1, k + 1);
    {
      const int kp = (k + 3 < kcnt) ? k + 3 : 0;
#pragma unroll
      for (int ks = 0; ks < 4; ++ks)
        a1[ks] = *(const short8*)(ap + (long)kp * PLANE + ks * 512);
    }
  }
  if (kcnt & 1) body(a0, kcnt - 1);

  // store bf16 half: msgout[kh][e][o]
#pragma unroll
  for (int ne = 0; ne < 4; ++ne) {
    const long e = e0 + we + ne * 16 + lo;
    uint2 pk;
    pk.x = (unsigned)f2bf(msg[ne][0]) | ((unsigned)f2bf(msg[ne][1]) << 16);
    pk.y = (unsigned)f2bf(msg[ne][2]) | ((unsigned)f2bf(msg[ne][3]) << 16);
    *(uint2*)(msgout + ((long)kh * NEDGES + e) * D + o0 + wo + hi * 4) = pk;
  }
}

// K4: 625 blocks x 16 nodes (byte-identical to round 8).
__global__ __launch_bounds__(256) void k4_out(
    const float* __restrict__ x, const unsigned short* __restrict__ rootT,
    const float* __restrict__ bias, const unsigned short* __restrict__ msg,
    const int* __restrict__ cnt, const int* __restrict__ elist,
    float* __restrict__ out) {
  __shared__ float segL[16 * 132];  // 8,448 B
  const int t = threadIdx.x;
  const int n0 = blockIdx.x * 16;
  // phase A: gather-sum msg rows per node (16 threads/node x 8 o)
  {
    const int ln = t >> 4;
    const int n = n0 + ln;
    const int os = (t & 15) * 8;
    float a[8];
#pragma unroll
    for (int i = 0; i < 8; ++i) a[i] = 0.f;
    if (n < NNODES) {
      const int deg = min(cnt[n], MAXDEG);
      for (int j = 0; j < deg; ++j) {
        const int e = elist[n * MAXDEG + j];
        const unsigned short* r0 = msg + (long)e * D + os;
        const unsigned short* r1 = r0 + (long)NEDGES * D;
        const uint4 u0 = *(const uint4*)r0;
        const uint4 u1 = *(const uint4*)r1;
        a[0] += bflo(u0.x) + bflo(u1.x);
        a[1] += bfhi(u0.x) + bfhi(u1.x);
        a[2] += bflo(u0.y) + bflo(u1.y);
        a[3] += bfhi(u0.y) + bfhi(u1.y);
        a[4] += bflo(u0.z) + bflo(u1.z);
        a[5] += bfhi(u0.z) + bfhi(u1.z);
        a[6] += bflo(u0.w) + bflo(u1.w);
        a[7] += bfhi(u0.w) + bfhi(u1.w);
      }
    }
    *(float4*)&segL[ln * 132 + os] = (float4){a[0], a[1], a[2], a[3]};
    *(float4*)&segL[ln * 132 + os + 4] = (float4){a[4], a[5], a[6], a[7]};
  }
  __syncthreads();
  // phase B: x@root MFMA; wave w owns o-slice w*32..w*32+32
  const int lane = t & 63, w = t >> 6, lo = lane & 15, hi = lane >> 4;
  const int nrow = n0 + lo;
  short8 af[4];
#pragma unroll
  for (int ks = 0; ks < 4; ++ks) {
    if (nrow < NNODES) {
      const float* p0 = x + (long)nrow * D + ks * 32 + hi * 8;
      af[ks] = pack8(*(const float4*)p0, *(const float4*)(p0 + 4));
    } else {
      af[ks] = (short8){0, 0, 0, 0, 0, 0, 0, 0};
    }
  }
  floatx4 acc[2];
#pragma unroll
  for (int nt = 0; nt < 2; ++nt) acc[nt] = (floatx4){0.f, 0.f, 0.f, 0.f};
#pragma unroll
  for (int ks = 0; ks < 4; ++ks) {
    const int ib = ks * 32 + hi * 8;
#pragma unroll
    for (int nt = 0; nt < 2; ++nt) {
      const short8 bf_ = *(const short8*)&rootT[(w * 32 + nt * 16 + lo) * PADR + ib];
      acc[nt] = __builtin_amdgcn_mfma_f32_16x16x32_bf16(af[ks], bf_, acc[nt], 0, 0, 0);
    }
  }
  float dinv[4];
#pragma unroll
  for (int r = 0; r < 4; ++r) {
    const int n = n0 + hi * 4 + r;
    dinv[r] = (n < NNODES) ? 1.0f / fmaxf((float)cnt[n], 1.0f) : 0.f;
  }
#pragma unroll
  for (int nt = 0; nt < 2; ++nt) {
    const int co = w * 32 + nt * 16 + lo;
    const float bv = bias[co];
#pragma unroll
    for (int r = 0; r < 4; ++r) {
      const int n = n0 + hi * 4 + r;
      if (n < NNODES) {
        const float aggr = segL[(hi * 4 + r) * 132 + co] * dinv[r];
        const float v = acc[nt][r] + aggr + bv;
        const float ge = 0.5f * v * (1.0f + erff(v * 0.70710678f));
        out[(long)n * D + co] = x[(long)n * D + co] + ge;
      }
    }
  }
}

extern "C" void kernel_launch(void* const* d_in, const int* in_sizes, int n_in,
                              void* d_out, int out_size, void* d_ws, size_t ws_size,
                              hipStream_t stream) {
  (void)in_sizes; (void)n_in; (void)out_size; (void)ws_size;
  const float* x    = (const float*)d_in[0];
  const int*   eidx = (const int*)d_in[1];
  const float* ea   = (const float*)d_in[2];
  const float* w1   = (const float*)d_in[3];
  const float* b1   = (const float*)d_in[4];
  const float* w2   = (const float*)d_in[5];
  const float* b2   = (const float*)d_in[6];
  const float* root = (const float*)d_in[7];
  const float* bias = (const float*)d_in[8];
  float* out = (float*)d_out;
  char* ws = (char*)d_ws;
  // ws layout (bytes):
  //   hT    @ 0          : 129*16384*2     = 4,227,072
  //   xjb   @ 4,227,072  : 16384*136*2     = 4,456,448
  //   w2t   @ 8,683,520  : 129*16384*2     = 4,227,072 (fragment layout)
  //   msg   @13,174,784  : 2*16384*128*2   = 8,388,608
  //   cnt   @21,563,392  : 40,000
  //   elist @21,603,392  : 640,000
  //   rootT @22,243,392  : 34,816          (total 22,278,208)
  unsigned short* hT    = (unsigned short*)(ws + 0);
  unsigned short* xjb   = (unsigned short*)(ws + 4227072);
  unsigned short* w2t   = (unsigned short*)(ws + 8683520);
  unsigned short* msg   = (unsigned short*)(ws + 13174784);
  int*            cnt   = (int*)(ws + 21563392);
  int*            elist = (int*)(ws + 21603392);
  unsigned short* rootT = (unsigned short*)(ws + 22243392);
  hipLaunchKernelGGL(k12, dim3(1032), dim3(256), 0, stream,
                     x, eidx, ea, w1, b1, w2, b2, root, w2t, rootT, hT, xjb, cnt);
  hipLaunchKernelGGL(k3_msg, dim3(1024), dim3(256), 0, stream,
                     w2t, xjb, hT, eidx, cnt, elist, msg);
  hipLaunchKernelGGL(k4_out, dim3((NNODES + 15) / 16), dim3(256), 0, stream,
                     x, rootT, bias, msg, cnt, elist, out);
}

// Round 10
// 162.860 us; speedup vs baseline: 1.3220x; 1.3220x over previous
//
#include <hip/hip_runtime.h>
#include <math.h>

#define D 128
#define NNODES 10000
#define NEDGES 16384
#define PADR 136   // bf16 row stride for xjb/rootT; 272B rows, 16B-aligned
#define MAXDEG 16

typedef short short8 __attribute__((ext_vector_type(8)));
typedef float floatx4 __attribute__((ext_vector_type(4)));

__device__ __forceinline__ float bf2f(unsigned short u) {
  union { unsigned u; float f; } v; v.u = ((unsigned)u) << 16; return v.f;
}
__device__ __forceinline__ unsigned short f2bf(float f) {
  union { float f; unsigned u; } v; v.f = f;
  return (unsigned short)((v.u + 0x7FFFu + ((v.u >> 16) & 1u)) >> 16);
}
__device__ __forceinline__ float bflo(unsigned u) {
  union { unsigned u; float f; } v; v.u = u << 16; return v.f;
}
__device__ __forceinline__ float bfhi(unsigned u) {
  union { unsigned u; float f; } v; v.u = u & 0xFFFF0000u; return v.f;
}
__device__ __forceinline__ short8 pack8(float4 a, float4 b) {
  short8 r;
  r[0] = (short)f2bf(a.x); r[1] = (short)f2bf(a.y);
  r[2] = (short)f2bf(a.z); r[3] = (short)f2bf(a.w);
  r[4] = (short)f2bf(b.x); r[5] = (short)f2bf(b.y);
  r[6] = (short)f2bf(b.z); r[7] = (short)f2bf(b.w);
  return r;
}

// K12: merged prep + edge kernel. Grid 1032 (byte-identical to round 8).
__global__ __launch_bounds__(256) void k12(
    const float* __restrict__ x, const int* __restrict__ eidx,
    const float* __restrict__ ea,
    const float* __restrict__ w1, const float* __restrict__ b1,
    const float* __restrict__ w2, const float* __restrict__ b2,
    const float* __restrict__ root,
    unsigned short* __restrict__ w2t, unsigned short* __restrict__ rootT,
    unsigned short* __restrict__ hT, unsigned short* __restrict__ xjb,
    int* __restrict__ cnt) {
  __shared__ float L[32][129];            // 16,512 B
  __shared__ unsigned short w1tL[128 * PADR];  // 34,816 B (edge path only)
  const int t = threadIdx.x;
  const int bid = blockIdx.x;

  if (bid < 520) {
    // ---------------- prep path ----------------
    if (bid < 40) { const int gid = bid * 256 + t; if (gid < NNODES) cnt[gid] = 0; }
    const float* __restrict__ src;
    int o0;
    if (bid < 516) {
      const int k = bid >> 2;
      o0 = (bid & 3) * 32;
      src = (k < D) ? (w2 + (long)k * (D * D)) : b2;
    } else {
      o0 = (bid - 516) * 32; src = root;
    }
#pragma unroll
    for (int r = 0; r < 16; ++r) {
      int idx = r * 256 + t;
      int i = idx >> 5, oc = idx & 31;
      L[oc][i] = src[i * D + o0 + oc];
    }
    __syncthreads();
#pragma unroll
    for (int r = 0; r < 8; ++r) {
      int p = r * 256 + t;
      int oc = p >> 6, i2 = (p & 63) * 2;
      unsigned v = (unsigned)f2bf(L[oc][i2]) | ((unsigned)f2bf(L[oc][i2 + 1]) << 16);
      if (bid < 516) {
        const long k = bid >> 2, oq = bid & 3;
        const int wg = oc >> 4, lo = oc & 15;
        const int ks = i2 >> 5, hi = (i2 & 31) >> 3, j = i2 & 7;
        const long off = ((((k * 4 + oq) * 2 + wg) * 4 + ks) * 512) +
                         (lo + 16 * hi) * 8 + j;
        *(unsigned*)(w2t + off) = v;
      } else {
        *(unsigned*)(rootT + ((o0 + oc) * PADR + i2)) = v;
      }
    }
    return;
  }

  // ---------------- edge path: 32 edges/block, w1t from LDS ----------------
  const int e0 = (bid - 520) * 32;
#pragma unroll 4
  for (int r = 0; r < 8; ++r) {
    int idx = r * 256 + t, e = idx >> 6, i2 = (idx & 63) * 2;
    const int s = eidx[e0 + e];
    const float2 v = *(const float2*)(x + (long)s * D + i2);
    unsigned p = (unsigned)f2bf(v.x) | ((unsigned)f2bf(v.y) << 16);
    *(unsigned*)(xjb + ((e0 + e) * PADR + i2)) = p;
  }
  for (int c = 0; c < 4; ++c) {
    const int o0c = c * 32;
#pragma unroll
    for (int r = 0; r < 16; ++r) {
      int idx = r * 256 + t;
      int i = idx >> 5, oc = idx & 31;
      L[oc][i] = w1[i * D + o0c + oc];
    }
    __syncthreads();
#pragma unroll
    for (int r = 0; r < 8; ++r) {
      int p = r * 256 + t;
      int oc = p >> 6, i2 = (p & 63) * 2;
      unsigned v = (unsigned)f2bf(L[oc][i2]) | ((unsigned)f2bf(L[oc][i2 + 1]) << 16);
      *(unsigned*)(w1tL + ((o0c + oc) * PADR + i2)) = v;
    }
    __syncthreads();
  }
  const int lane = t & 63, w = t >> 6, lo = lane & 15, hi = lane >> 4;
  const int e16 = (w & 1) * 16;     // wave's 16-edge group
  const int kh = (w >> 1) * 64;     // wave's k-half
  short8 af[4];
#pragma unroll
  for (int ks = 0; ks < 4; ++ks) {
    const float* p0 = ea + (long)(e0 + e16 + lo) * D + ks * 32 + hi * 8;
    af[ks] = pack8(*(const float4*)p0, *(const float4*)(p0 + 4));
  }
  floatx4 acc[4];
#pragma unroll
  for (int nt = 0; nt < 4; ++nt) acc[nt] = (floatx4){0.f, 0.f, 0.f, 0.f};
#pragma unroll
  for (int ks = 0; ks < 4; ++ks) {
    const int ib = ks * 32 + hi * 8;
#pragma unroll
    for (int nt = 0; nt < 4; ++nt) {
      const short8 bf_ = *(const short8*)&w1tL[(kh + nt * 16 + lo) * PADR + ib];
      acc[nt] = __builtin_amdgcn_mfma_f32_16x16x32_bf16(af[ks], bf_, acc[nt], 0, 0, 0);
    }
  }
#pragma unroll
  for (int nt = 0; nt < 4; ++nt) {
    const int ko = kh + nt * 16 + lo;
    const float b1v = b1[ko];
    float v0 = fmaxf(acc[nt][0] + b1v, 0.f);
    float v1 = fmaxf(acc[nt][1] + b1v, 0.f);
    float v2 = fmaxf(acc[nt][2] + b1v, 0.f);
    float v3 = fmaxf(acc[nt][3] + b1v, 0.f);
    uint2 pk;
    pk.x = (unsigned)f2bf(v0) | ((unsigned)f2bf(v1) << 16);
    pk.y = (unsigned)f2bf(v2) | ((unsigned)f2bf(v3) << 16);
    *(uint2*)(hT + (ko * NEDGES + e0 + e16 + hi * 4)) = pk;
  }
  if (t < 32) hT[128 * NEDGES + e0 + t] = 0x3F80;  // bf16(1.0) ones-row (b2)
}

// K3 = round-7/8 proven structure at (256,3) — round-9's (256,4) spilled
// (VGPR forced to 64, WRITE 9->36MB) and is closed. ONE delta vs round 8:
// triple-buffered A (a0/a1/a2, 2-body ~1000cy prefetch distance). Round-8
// FETCH showed w2t at 4.5x its size from HBM -> A latency is ~900cy HBM-class,
// which the old 1-body (~300-500cy) double-buffer cannot cover.
// Regs: ~116 + 16 = ~132 < 170/wave budget at 3 waves/SIMD -> no spill.
__global__ __launch_bounds__(256, 3) void k3_msg(
    const unsigned short* __restrict__ w2t,
    const unsigned short* __restrict__ xjb,
    const unsigned short* __restrict__ hT,
    const int* __restrict__ eidx, int* __restrict__ cnt,
    int* __restrict__ elist,
    unsigned short* __restrict__ msgout) {
  __shared__ float hLT[65 * 128];   // 33,280 B; idx = kk*128 + (e>>6)*64 + (e&15)*4 + ((e>>4)&3)
  const int t = threadIdx.x;
  const int b = blockIdx.x;
  const int kh = b & 1;
  const int oq = (b >> 1) & 3;      // (oq,kh) fixed per XCD -> w2t slice L2-hot
  const int eg = b >> 3;
  const int e0 = eg * 128;
  const int o0 = oq * 32;
  const int kbase = kh * 64;
  const int kcnt = kh ? 65 : 64;    // kh1 includes k=128 (b2 ones-row)
  const int lane = t & 63, wv = t >> 6;
  const int lo = lane & 15, hi = lane >> 4;
  const int we = (wv >> 1) * 64;
  const int wg = wv & 1;            // o-group (wo = wg*16)
  const int wo = wg * 16;

  // adjacency build (cnt zeroed by k12, prior dispatch)
  if ((b & 7) == 0 && t < 128) {
    const int e = e0 + t;
    const int d = eidx[NEDGES + e];
    const int pos = atomicAdd(&cnt[d], 1);
    if (pos < MAXDEG) elist[d * MAXDEG + pos] = e;
  }

  // stage hLT (permuted) from hT; 2 edges per thread-iter
  for (int idx = t; idx < kcnt * 64; idx += 256) {
    const int kk = idx >> 6, e2 = (idx & 63) * 2;
    const unsigned u = *(const unsigned*)&hT[(long)(kbase + kk) * NEDGES + e0 + e2];
    const int ebase = kk * 128;
#pragma unroll
    for (int q = 0; q < 2; ++q) {
      const int e = e2 + q;
      hLT[ebase + ((e >> 6) << 6) + ((e & 15) << 2) + ((e >> 4) & 3)] =
          q ? bfhi(u) : bflo(u);
    }
  }

  // xf from xjb (k-invariant, b128, no conversion)
  short8 xf[4][4];
#pragma unroll
  for (int ne = 0; ne < 4; ++ne)
#pragma unroll
    for (int ks = 0; ks < 4; ++ks)
      xf[ne][ks] = *(const short8*)&xjb[(long)(e0 + we + ne * 16 + lo) * PADR + ks * 32 + hi * 8];
  __syncthreads();  // the only barrier

  // fragment-packed A: frag(k, ks) at ((((k*4+oq)*2+wg)*4+ks)*512 + lane*8
  const long PLANE = (long)D * D;   // 16384 shorts between consecutive k
  const unsigned short* ap =
      w2t + ((((long)kbase * 4 + oq) * 2 + wg) * 4) * 512 + lane * 8;
  const float* hp = hLT + we + lo * 4;

  auto ldk = [&](short8* dst, int k) {
    const int kp = (k < kcnt) ? k : 0;   // clamp: benign reload of plane 0
#pragma unroll
    for (int ks = 0; ks < 4; ++ks)
      dst[ks] = *(const short8*)(ap + (long)kp * PLANE + ks * 512);
  };

  short8 a0[4], a1[4], a2[4];
  ldk(a0, 0); ldk(a1, 1); ldk(a2, 2);
  floatx4 msg[4];
#pragma unroll
  for (int ne = 0; ne < 4; ++ne) msg[ne] = (floatx4){0.f, 0.f, 0.f, 0.f};

  auto body = [&](short8* fr, int k) {
    const floatx4 h4 = *(const floatx4*)(hp + k * 128);
    floatx4 P[4];
#pragma unroll
    for (int ne = 0; ne < 4; ++ne) P[ne] = (floatx4){0.f, 0.f, 0.f, 0.f};
#pragma unroll
    for (int ks = 0; ks < 4; ++ks)
#pragma unroll
      for (int ne = 0; ne < 4; ++ne)
        P[ne] = __builtin_amdgcn_mfma_f32_16x16x32_bf16(fr[ks], xf[ne][ks], P[ne], 0, 0, 0);
#pragma unroll
    for (int ne = 0; ne < 4; ++ne)
#pragma unroll
      for (int r = 0; r < 4; ++r) msg[ne][r] += h4[ne] * P[ne][r];
  };

  int j;
  for (j = 0; j + 3 <= kcnt; j += 3) {
    body(a0, j);     ldk(a0, j + 3);
    body(a1, j + 1); ldk(a1, j + 4);
    body(a2, j + 2); ldk(a2, j + 5);
  }
  if (j < kcnt)     body(a0, j);         // kcnt=64: j=63 / kcnt=65: j=63
  if (j + 1 < kcnt) body(a1, j + 1);     // kcnt=65: j+1=64 (b2 ones-row)

  // store bf16 half: msgout[kh][e][o]
#pragma unroll
  for (int ne = 0; ne < 4; ++ne) {
    const long e = e0 + we + ne * 16 + lo;
    uint2 pk;
    pk.x = (unsigned)f2bf(msg[ne][0]) | ((unsigned)f2bf(msg[ne][1]) << 16);
    pk.y = (unsigned)f2bf(msg[ne][2]) | ((unsigned)f2bf(msg[ne][3]) << 16);
    *(uint2*)(msgout + ((long)kh * NEDGES + e) * D + o0 + wo + hi * 4) = pk;
  }
}

// K4: 625 blocks x 16 nodes (byte-identical to round 8).
__global__ __launch_bounds__(256) void k4_out(
    const float* __restrict__ x, const unsigned short* __restrict__ rootT,
    const float* __restrict__ bias, const unsigned short* __restrict__ msg,
    const int* __restrict__ cnt, const int* __restrict__ elist,
    float* __restrict__ out) {
  __shared__ float segL[16 * 132];  // 8,448 B
  const int t = threadIdx.x;
  const int n0 = blockIdx.x * 16;
  // phase A: gather-sum msg rows per node (16 threads/node x 8 o)
  {
    const int ln = t >> 4;
    const int n = n0 + ln;
    const int os = (t & 15) * 8;
    float a[8];
#pragma unroll
    for (int i = 0; i < 8; ++i) a[i] = 0.f;
    if (n < NNODES) {
      const int deg = min(cnt[n], MAXDEG);
      for (int j = 0; j < deg; ++j) {
        const int e = elist[n * MAXDEG + j];
        const unsigned short* r0 = msg + (long)e * D + os;
        const unsigned short* r1 = r0 + (long)NEDGES * D;
        const uint4 u0 = *(const uint4*)r0;
        const uint4 u1 = *(const uint4*)r1;
        a[0] += bflo(u0.x) + bflo(u1.x);
        a[1] += bfhi(u0.x) + bfhi(u1.x);
        a[2] += bflo(u0.y) + bflo(u1.y);
        a[3] += bfhi(u0.y) + bfhi(u1.y);
        a[4] += bflo(u0.z) + bflo(u1.z);
        a[5] += bfhi(u0.z) + bfhi(u1.z);
        a[6] += bflo(u0.w) + bflo(u1.w);
        a[7] += bfhi(u0.w) + bfhi(u1.w);
      }
    }
    *(float4*)&segL[ln * 132 + os] = (float4){a[0], a[1], a[2], a[3]};
    *(float4*)&segL[ln * 132 + os + 4] = (float4){a[4], a[5], a[6], a[7]};
  }
  __syncthreads();
  // phase B: x@root MFMA; wave w owns o-slice w*32..w*32+32
  const int lane = t & 63, w = t >> 6, lo = lane & 15, hi = lane >> 4;
  const int nrow = n0 + lo;
  short8 af[4];
#pragma unroll
  for (int ks = 0; ks < 4; ++ks) {
    if (nrow < NNODES) {
      const float* p0 = x + (long)nrow * D + ks * 32 + hi * 8;
      af[ks] = pack8(*(const float4*)p0, *(const float4*)(p0 + 4));
    } else {
      af[ks] = (short8){0, 0, 0, 0, 0, 0, 0, 0};
    }
  }
  floatx4 acc[2];
#pragma unroll
  for (int nt = 0; nt < 2; ++nt) acc[nt] = (floatx4){0.f, 0.f, 0.f, 0.f};
#pragma unroll
  for (int ks = 0; ks < 4; ++ks) {
    const int ib = ks * 32 + hi * 8;
#pragma unroll
    for (int nt = 0; nt < 2; ++nt) {
      const short8 bf_ = *(const short8*)&rootT[(w * 32 + nt * 16 + lo) * PADR + ib];
      acc[nt] = __builtin_amdgcn_mfma_f32_16x16x32_bf16(af[ks], bf_, acc[nt], 0, 0, 0);
    }
  }
  float dinv[4];
#pragma unroll
  for (int r = 0; r < 4; ++r) {
    const int n = n0 + hi * 4 + r;
    dinv[r] = (n < NNODES) ? 1.0f / fmaxf((float)cnt[n], 1.0f) : 0.f;
  }
#pragma unroll
  for (int nt = 0; nt < 2; ++nt) {
    const int co = w * 32 + nt * 16 + lo;
    const float bv = bias[co];
#pragma unroll
    for (int r = 0; r < 4; ++r) {
      const int n = n0 + hi * 4 + r;
      if (n < NNODES) {
        const float aggr = segL[(hi * 4 + r) * 132 + co] * dinv[r];
        const float v = acc[nt][r] + aggr + bv;
        const float ge = 0.5f * v * (1.0f + erff(v * 0.70710678f));
        out[(long)n * D + co] = x[(long)n * D + co] + ge;
      }
    }
  }
}

extern "C" void kernel_launch(void* const* d_in, const int* in_sizes, int n_in,
                              void* d_out, int out_size, void* d_ws, size_t ws_size,
                              hipStream_t stream) {
  (void)in_sizes; (void)n_in; (void)out_size; (void)ws_size;
  const float* x    = (const float*)d_in[0];
  const int*   eidx = (const int*)d_in[1];
  const float* ea   = (const float*)d_in[2];
  const float* w1   = (const float*)d_in[3];
  const float* b1   = (const float*)d_in[4];
  const float* w2   = (const float*)d_in[5];
  const float* b2   = (const float*)d_in[6];
  const float* root = (const float*)d_in[7];
  const float* bias = (const float*)d_in[8];
  float* out = (float*)d_out;
  char* ws = (char*)d_ws;
  // ws layout (bytes):
  //   hT    @ 0          : 129*16384*2     = 4,227,072
  //   xjb   @ 4,227,072  : 16384*136*2     = 4,456,448
  //   w2t   @ 8,683,520  : 129*16384*2     = 4,227,072 (fragment layout)
  //   msg   @13,174,784  : 2*16384*128*2   = 8,388,608
  //   cnt   @21,563,392  : 40,000
  //   elist @21,603,392  : 640,000
  //   rootT @22,243,392  : 34,816          (total 22,278,208)
  unsigned short* hT    = (unsigned short*)(ws + 0);
  unsigned short* xjb   = (unsigned short*)(ws + 4227072);
  unsigned short* w2t   = (unsigned short*)(ws + 8683520);
  unsigned short* msg   = (unsigned short*)(ws + 13174784);
  int*            cnt   = (int*)(ws + 21563392);
  int*            elist = (int*)(ws + 21603392);
  unsigned short* rootT = (unsigned short*)(ws + 22243392);
  hipLaunchKernelGGL(k12, dim3(1032), dim3(256), 0, stream,
                     x, eidx, ea, w1, b1, w2, b2, root, w2t, rootT, hT, xjb, cnt);
  hipLaunchKernelGGL(k3_msg, dim3(1024), dim3(256), 0, stream,
                     w2t, xjb, hT, eidx, cnt, elist, msg);
  hipLaunchKernelGGL(k4_out, dim3((NNODES + 15) / 16), dim3(256), 0, stream,
                     x, rootT, bias, msg, cnt, elist, out);
}